// Round 1
// baseline (126.124 us; speedup 1.0000x reference)
//
#include <hip/hip_runtime.h>
#include <hip/hip_bf16.h>

typedef __attribute__((ext_vector_type(8))) short bf16x8;
typedef __attribute__((ext_vector_type(4))) float f32x4;

static __device__ inline unsigned short f2bf(float f) {
    unsigned int u = __float_as_uint(f);
    unsigned int r = (u + 0x7fff + ((u >> 16) & 1)) >> 16;
    return (unsigned short)r;
}

// ---------------- prep kernels ----------------

// u[h][5] from centers/spreads
__global__ void k_u(const float* __restrict__ centers, const float* __restrict__ spreads,
                    float* __restrict__ u) {
    int h = threadIdx.x;
    if (h < 8) {
        float s00 = spreads[h*4+0], s01 = spreads[h*4+1];
        float s10 = spreads[h*4+2], s11 = spreads[h*4+3];
        float a  = s00*s00 + s01*s01;
        float bb = s00*s10 + s01*s11;
        float c  = s10*s10 + s11*s11;
        float m1 = centers[h*2+0], m2 = centers[h*2+1];
        u[h*5+0] = a*m1 + bb*m2;
        u[h*5+1] = c*m2 + bb*m1;
        u[h*5+2] = -0.5f*a;
        u[h*5+3] = -0.5f*c;
        u[h*5+4] = -bb;
    }
}

// Etab[h][dk][dl] = exp(g_h(dk-31, dl-31)),  8*63*63
__global__ void k_etab(const float* __restrict__ u, float* __restrict__ Etab) {
    int idx = blockIdx.x*256 + threadIdx.x;
    if (idx >= 8*3969) return;
    int h = idx / 3969, r = idx % 3969;
    float d1 = (float)(r/63 - 31), d2 = (float)(r%63 - 31);
    const float* uh = u + h*5;
    float g = d1*uh[0] + d2*uh[1] + d1*d1*uh[2] + d2*d2*uh[3] + d1*d2*uh[4];
    Etab[idx] = expf(g);
}

// invZ[ij][h] = 1 / sum_{k,l} Etab[h][k-i+31][l-j+31]
__global__ void k_z(const float* __restrict__ Etab, float* __restrict__ invZ) {
    int ij = blockIdx.x;
    int i = ij >> 5, j = ij & 31;
    int t = threadIdx.x;
    int h = t >> 5, k = t & 31;
    const float* Eh = Etab + h*3969 + (k - i + 31)*63 + (31 - j);
    float s = 0.f;
    #pragma unroll
    for (int l = 0; l < 32; ++l) s += Eh[l];
    #pragma unroll
    for (int m = 16; m >= 1; m >>= 1) s += __shfl_xor(s, m);
    if (k == 0) invZ[ij*8 + h] = 1.0f / s;
}

// X2[(b*64+e)][kl] = bf16(X[b][kl][e])   (2048 x 1024)
__global__ void k_x2(const float* __restrict__ X, unsigned short* __restrict__ X2) {
    __shared__ float t[64][65];
    int b = blockIdx.y, kl0 = blockIdx.x * 64;
    const float* Xb = X + (size_t)b * 65536;
    #pragma unroll
    for (int it = 0; it < 16; ++it) {
        int flat = it*256 + threadIdx.x;
        int kl = flat >> 6, e = flat & 63;
        t[e][kl] = Xb[(size_t)(kl0 + kl)*64 + e];
    }
    __syncthreads();
    #pragma unroll
    for (int it = 0; it < 16; ++it) {
        int flat = it*256 + threadIdx.x;
        int e = flat >> 6, kl = flat & 63;
        X2[((size_t)(b*64 + e) << 10) + kl0 + kl] = f2bf(t[e][kl]);
    }
}

// fcwb[e'][f] = bf16(fc_w[e'][f])   (64 x 512)
__global__ void k_fcwb(const float* __restrict__ fc_w, unsigned short* __restrict__ fcwb) {
    int idx = blockIdx.x*1024 + threadIdx.x*4;
    float4 v = *(const float4*)(fc_w + idx);
    ushort4 o;
    o.x = f2bf(v.x); o.y = f2bf(v.y); o.z = f2bf(v.z); o.w = f2bf(v.w);
    *(ushort4*)(fcwb + idx) = o;
}

// P[r][kl] = bf16(Etab[h][k-i+31][l-j+31] * invZ[r]),  r = (ij)*8+h,  8192 x 1024
__global__ void k_p(const float* __restrict__ Etab, const float* __restrict__ invZ,
                    unsigned short* __restrict__ P) {
    int t = blockIdx.x*256 + threadIdx.x;    // [0, 2097152)
    int r = t >> 8;
    int g = t & 255;
    int kl0 = g * 4;
    int k = kl0 >> 5, l0 = kl0 & 31;
    int ij = r >> 3, h = r & 7;
    int i = ij >> 5, j = ij & 31;
    const float* Ep = Etab + h*3969 + (k - i + 31)*63 + (l0 - j + 31);
    float z = invZ[r];
    ushort4 o;
    o.x = f2bf(Ep[0]*z); o.y = f2bf(Ep[1]*z); o.z = f2bf(Ep[2]*z); o.w = f2bf(Ep[3]*z);
    *(ushort4*)(P + ((size_t)r << 10) + kl0) = o;
}

// ---------------- main GEMM + fused fc epilogue ----------------
// AH[(ij,h),(b,e)] = sum_kl P[(ij,h),kl] * X2[(b,e),kl]
// tile: 128 rows (16 ij x 8 h) x 256 cols (4 b x 64 e), K = 1024, BK = 64
// epilogue: out[b,i,j,e'] = sum_{e,h} AH * fcw[e'][e*8+h] + fc_b[e']
__global__ __launch_bounds__(512) void k_gemm(const unsigned short* __restrict__ P,
                                              const unsigned short* __restrict__ X2,
                                              const unsigned short* __restrict__ fcwb,
                                              const float* __restrict__ fc_b,
                                              float* __restrict__ out) {
    union Sh {
        struct { short A[128*64]; short B[256*64]; } s;  // 48 KB
        short AHe[64*520];                                // 66560 B (padded rows)
    };
    __shared__ Sh sh;

    int tid = threadIdx.x;
    int lane = tid & 63, wid = tid >> 6;
    int lr = lane & 15, lk = lane >> 4;
    int m0 = blockIdx.x * 128, n0 = blockIdx.y * 256;
    int wr = wid >> 2, wc = wid & 3;   // wave covers rows [wr*64, +64), cols [wc*64, +64)

    f32x4 acc[4][4] = {};

    for (int kt = 0; kt < 16; ++kt) {
        int K0 = kt * 64;
        // stage A: 1024 16B-chunks; LDS linear, source XOR-swizzled (chunk-in-row ^= row&7)
        #pragma unroll
        for (int it = 0; it < 2; ++it) {
            int chunk = it*512 + wid*64 + lane;
            int r = chunk >> 3, cs = chunk & 7;
            const unsigned short* g = P + (size_t)(m0 + r)*1024 + K0 + ((cs ^ (r & 7)) << 3);
            __builtin_amdgcn_global_load_lds(
                (const __attribute__((address_space(1))) void*)g,
                (__attribute__((address_space(3))) void*)(&sh.s.A[(it*512 + wid*64) * 8]),
                16, 0, 0);
        }
        // stage B: 2048 chunks
        #pragma unroll
        for (int it = 0; it < 4; ++it) {
            int chunk = it*512 + wid*64 + lane;
            int r = chunk >> 3, cs = chunk & 7;
            const unsigned short* g = X2 + (size_t)(n0 + r)*1024 + K0 + ((cs ^ (r & 7)) << 3);
            __builtin_amdgcn_global_load_lds(
                (const __attribute__((address_space(1))) void*)g,
                (__attribute__((address_space(3))) void*)(&sh.s.B[(it*512 + wid*64) * 8]),
                16, 0, 0);
        }
        __syncthreads();
        #pragma unroll
        for (int kk = 0; kk < 2; ++kk) {
            bf16x8 av[4], bv[4];
            #pragma unroll
            for (int m = 0; m < 4; ++m) {
                int row = wr*64 + m*16 + lr;
                int c = kk*4 + lk;
                int cs = c ^ (row & 7);
                av[m] = *(const bf16x8*)&sh.s.A[row*64 + cs*8];
            }
            #pragma unroll
            for (int n = 0; n < 4; ++n) {
                int col = wc*64 + n*16 + lr;
                int c = kk*4 + lk;
                int cs = c ^ (col & 7);
                bv[n] = *(const bf16x8*)&sh.s.B[col*64 + cs*8];
            }
            #pragma unroll
            for (int m = 0; m < 4; ++m)
                #pragma unroll
                for (int n = 0; n < 4; ++n)
                    acc[m][n] = __builtin_amdgcn_mfma_f32_16x16x32_bf16(av[m], bv[n], acc[m][n], 0, 0, 0);
        }
        __syncthreads();
    }

    // scatter acc -> AHe[bij_local][f] as bf16 (reuses A/B LDS; barrier above protects)
    #pragma unroll
    for (int m = 0; m < 4; ++m) {
        #pragma unroll
        for (int n = 0; n < 4; ++n) {
            int colC = wc*64 + n*16 + lr;        // (b,e) local
            int bb = colC >> 6, e = colC & 63;
            #pragma unroll
            for (int reg = 0; reg < 4; ++reg) {
                int rowC = wr*64 + m*16 + lk*4 + reg;   // (ij,h) local
                int jj = rowC >> 3, hh = rowC & 7;
                sh.AHe[(bb*16 + jj)*520 + e*8 + hh] = (short)f2bf(acc[m][n][reg]);
            }
        }
    }
    __syncthreads();

    // mini-GEMM: out2[r2][e'] = sum_f AHe[r2][f] * fcwb[e'][f]; M=64, N=64, K=512
    int fm = wid >> 1, fn0 = (wid & 1) * 2;
    f32x4 facc[2] = {};
    #pragma unroll
    for (int ks = 0; ks < 16; ++ks) {
        int koff = ks*32 + lk*8;
        bf16x8 a  = *(const bf16x8*)&sh.AHe[(fm*16 + lr)*520 + koff];
        bf16x8 b0 = *(const bf16x8*)&fcwb[(size_t)(fn0*16 + lr)*512 + koff];
        bf16x8 b1 = *(const bf16x8*)&fcwb[(size_t)((fn0+1)*16 + lr)*512 + koff];
        facc[0] = __builtin_amdgcn_mfma_f32_16x16x32_bf16(a, b0, facc[0], 0, 0, 0);
        facc[1] = __builtin_amdgcn_mfma_f32_16x16x32_bf16(a, b1, facc[1], 0, 0, 0);
    }

    int i_blk = blockIdx.x >> 1;
    int j0 = (blockIdx.x & 1) * 16;
    int b0g = blockIdx.y * 4;
    #pragma unroll
    for (int f = 0; f < 2; ++f) {
        int ecol = (fn0 + f)*16 + lr;
        float bias = fc_b[ecol];
        #pragma unroll
        for (int reg = 0; reg < 4; ++reg) {
            int r2 = fm*16 + lk*4 + reg;
            int b = b0g + (r2 >> 4), jj = r2 & 15;
            size_t o = (((size_t)(b*32 + i_blk))*32 + (j0 + jj))*64 + ecol;
            out[o] = facc[f][reg] + bias;
        }
    }
}

extern "C" void kernel_launch(void* const* d_in, const int* in_sizes, int n_in,
                              void* d_out, int out_size, void* d_ws, size_t ws_size,
                              hipStream_t stream) {
    const float* X       = (const float*)d_in[0];
    // d_in[1] = attention_mask (unused by reference)
    const float* centers = (const float*)d_in[2];
    const float* spreads = (const float*)d_in[3];
    const float* fc_w    = (const float*)d_in[4];
    const float* fc_b    = (const float*)d_in[5];
    float* out = (float*)d_out;

    char* ws = (char*)d_ws;
    float* u            = (float*)ws;                      // 160 B
    float* Etab         = (float*)(ws + 4096);             // 127,008 B
    float* invZ         = (float*)(ws + (144 << 10));      // 32 KB
    unsigned short* fcwb = (unsigned short*)(ws + (256 << 10)); // 64 KB
    unsigned short* X2   = (unsigned short*)(ws + (512 << 10)); // 4 MB
    unsigned short* P    = (unsigned short*)(ws + (size_t)(5 << 20)); // 16 MB

    k_u    <<<1, 64, 0, stream>>>(centers, spreads, u);
    k_etab <<<125, 256, 0, stream>>>(u, Etab);
    k_z    <<<1024, 256, 0, stream>>>(Etab, invZ);
    k_x2   <<<dim3(16, 32), 256, 0, stream>>>(X, X2);
    k_fcwb <<<32, 256, 0, stream>>>(fc_w, fcwb);
    k_p    <<<8192, 256, 0, stream>>>(Etab, invZ, P);
    k_gemm <<<dim3(64, 8), 512, 0, stream>>>(P, X2, fcwb, fc_b, out);
}